// Round 19
// baseline (163.316 us; speedup 1.0000x reference)
//
#include <hip/hip_runtime.h>

#define NB 8
#define NN 512
#define ND 64
#define NKEEP 256
#define PJ 132
#define WSCALE 2.8853900817779268f   // 2*log2(e): MFMA acc = 2*zeta*log2(e)
#define K2 0.72134752f               // log2(e)/2

#define SELU_SCALE 1.0507009873554805f
#define SELU_ALPHA 1.6732632423543773f

typedef __attribute__((ext_vector_type(8))) short short8;
typedef __attribute__((ext_vector_type(4))) float f32x4;

__device__ __forceinline__ unsigned short f2bf_rne(float f) {
    unsigned u = __float_as_uint(f);
    return (unsigned short)((u + 0x7fffu + ((u >> 16) & 1u)) >> 16);
}
__device__ __forceinline__ float bf2f(unsigned short h) {
    return __uint_as_float(((unsigned)h) << 16);
}

// async global->LDS, 16 bytes per lane; lds dest = wave-uniform base (+lane*16 in HW)
__device__ __forceinline__ void gl2lds16(const unsigned short* g, unsigned short* l) {
    __builtin_amdgcn_global_load_lds(
        (const __attribute__((address_space(1))) unsigned int*)g,
        (__attribute__((address_space(3))) unsigned int*)l,
        16, 0, 0);
}
__device__ __forceinline__ void gl2lds16f(const float* g, float* l) {
    __builtin_amdgcn_global_load_lds(
        (const __attribute__((address_space(1))) unsigned int*)g,
        (__attribute__((address_space(3))) unsigned int*)l,
        16, 0, 0);
}

// convert one float4 of x into swizzled bf16 hi/lo LDS image
__device__ __forceinline__ void cvt_store(float4 v, unsigned short* Xh,
                                          unsigned short* Xl, int idx) {
    unsigned short h0 = f2bf_rne(v.x), h1 = f2bf_rne(v.y),
                   h2 = f2bf_rne(v.z), h3 = f2bf_rne(v.w);
    unsigned short l0 = (unsigned short)(__float_as_uint(v.x - bf2f(h0)) >> 16);
    unsigned short l1 = (unsigned short)(__float_as_uint(v.y - bf2f(h1)) >> 16);
    unsigned short l2 = (unsigned short)(__float_as_uint(v.z - bf2f(h2)) >> 16);
    unsigned short l3 = (unsigned short)(__float_as_uint(v.w - bf2f(h3)) >> 16);
    *(uint2*)(&Xh[idx]) = make_uint2((unsigned)h0 | ((unsigned)h1 << 16),
                                     (unsigned)h2 | ((unsigned)h3 << 16));
    *(uint2*)(&Xl[idx]) = make_uint2((unsigned)l0 | ((unsigned)l1 << 16),
                                     (unsigned)l2 | ((unsigned)l3 << 16));
}

// Phase 1 (R18-exact): upper-triangle logits, R13 round-balanced decode,
// inline x->bf16 hi/lo conversion (no prep kernel), restage early-issued
// after SYNC1 and converted before SYNC2.
__global__ __launch_bounds__(512, 4)
void sast_logit_kernel(const float* __restrict__ x,
                       const float* __restrict__ att_w,
                       const float* __restrict__ att_b,
                       const float* __restrict__ att_wt,
                       unsigned short* __restrict__ p_buf)
{
    __shared__ alignas(16) unsigned short Xh[8192];   // 16 KB swizzled image
    __shared__ alignas(16) unsigned short Xl[8192];
    __shared__ float probs[4 * PJ];
    __shared__ float lpP[4 * PJ];
    __shared__ float xg[4 * ND];

    const int tid  = threadIdx.x;
    const int w    = tid >> 6;          // wave 0..7
    const int iw   = w & 3;             // local i
    const int eh   = w >> 2;            // e-half 0/1
    const int lane = tid & 63;
    const int g    = lane >> 4;
    const int rr   = lane & 15;
    // round-balanced decode (R13)
    const int rnd  = blockIdx.x >> 8;          // 0..3 == c0
    const int m0   = blockIdx.x & 31;
    const int m    = (rnd & 1) ? (31 - m0) : m0;
    const int b    = (blockIdx.x >> 5) & 7;
    const int i0   = 128 * rnd + 4 * m;
    const int c0   = rnd;

    const float* xf = x + b * NN * ND;
    unsigned short* pb = p_buf + b * NN * NN;

    // conversion job: row rj (0..127) of chunk, float4s q0..q0+3
    const int rj = tid >> 2;
    const int q0 = (tid & 3) * 4;
    const int sw = (rj & 7) << 3;

    // nLam2 = -log2e * 0.5 * sum_e |attw|
    float sab = 0.f;
    #pragma unroll
    for (int e4 = 0; e4 < ND; e4 += 4) {
        float4 awv = *(const float4*)(att_wt + e4);
        sab += fabsf(awv.x) + fabsf(awv.y) + fabsf(awv.z) + fabsf(awv.w);
    }
    const float nLam2 = -K2 * sab;

    const int swz = (rr & 7) << 3;
    const int fb0 = rr * 64 + ((g * 8) ^ swz);
    const int fb1 = rr * 64 + ((g * 8 + 32) ^ swz);

    // ---- stage x_i rows ----
    if (tid < 256) xg[tid] = x[(b * NN + i0 + (tid >> 6)) * ND + (tid & 63)];

    // ---- chunk-c0 conversion BEFORE W-build ----
    {
        const float* src = xf + (c0 * 128 + rj) * ND + q0 * 4;
        float4 v0 = *(const float4*)(src);
        float4 v1 = *(const float4*)(src + 4);
        float4 v2 = *(const float4*)(src + 8);
        float4 v3 = *(const float4*)(src + 12);
        cvt_store(v0, Xh, Xl, rj * 64 + (((q0 + 0) * 4) ^ sw));
        cvt_store(v1, Xh, Xl, rj * 64 + (((q0 + 1) * 4) ^ sw));
        cvt_store(v2, Xh, Xl, rj * 64 + (((q0 + 2) * 4) ^ sw));
        cvt_store(v3, Xh, Xl, rj * 64 + (((q0 + 3) * 4) ^ sw));
    }
    __syncthreads();                 // xg + chunk-c0 image visible

    // W_i fragments for THIS e-half, hi/lo bf16, x 2log2e
    short8 Wh[2][2], Wl[2][2];
    #pragma unroll
    for (int mt2 = 0; mt2 < 2; ++mt2) {
        const int mt = eh * 2 + mt2;
        #pragma unroll
        for (int ks = 0; ks < 2; ++ks) {
            #pragma unroll
            for (int t = 0; t < 8; ++t) {
                int d = ks * 32 + g * 8 + t;
                int e = mt * 16 + rr;
                float wv = att_w[d * ND + e] * xg[iw * ND + d] * WSCALE;
                unsigned short hh = f2bf_rne(wv);
                unsigned short ll = (unsigned short)(__float_as_uint(wv - bf2f(hh)) >> 16);
                Wh[mt2][ks][t] = (short)hh;
                Wl[mt2][ks][t] = (short)ll;
            }
        }
    }
    f32x4 attb4[2], mw4[2];
    float basep = 0.f;
    #pragma unroll
    for (int mt2 = 0; mt2 < 2; ++mt2) {
        const int mt = eh * 2 + mt2;
        #pragma unroll
        for (int r = 0; r < 4; ++r) {
            int e = mt * 16 + g * 4 + r;
            float aw = att_wt[e];
            attb4[mt2][r] = att_b[e] * WSCALE;
            mw4[mt2][r]   = -2.0f * aw;
            basep += aw;
        }
    }

    for (int c = c0; c < 4; ++c) {
        const int jb = c << 7;
        const int jt0 = (i0 > jb) ? ((i0 - jb) >> 4) : 0;  // skip tiles below boundary

        float lp_own[8];
        #pragma unroll
        for (int jt = jt0; jt < 8; ++jt) {
            short8 bh0 = *(const short8*)(Xh + fb0 + jt * 1024);
            short8 bh1 = *(const short8*)(Xh + fb1 + jt * 1024);
            short8 bl0 = *(const short8*)(Xl + fb0 + jt * 1024);
            short8 bl1 = *(const short8*)(Xl + fb1 + jt * 1024);
            float lp = basep;
            #pragma unroll
            for (int mt2 = 0; mt2 < 2; ++mt2) {
                f32x4 acc = attb4[mt2];
                acc = __builtin_amdgcn_mfma_f32_16x16x32_bf16(Wh[mt2][0], bh0, acc, 0, 0, 0);
                acc = __builtin_amdgcn_mfma_f32_16x16x32_bf16(Wh[mt2][1], bh1, acc, 0, 0, 0);
                acc = __builtin_amdgcn_mfma_f32_16x16x32_bf16(Wh[mt2][0], bl0, acc, 0, 0, 0);
                acc = __builtin_amdgcn_mfma_f32_16x16x32_bf16(Wh[mt2][1], bl1, acc, 0, 0, 0);
                acc = __builtin_amdgcn_mfma_f32_16x16x32_bf16(Wl[mt2][0], bh0, acc, 0, 0, 0);
                acc = __builtin_amdgcn_mfma_f32_16x16x32_bf16(Wl[mt2][1], bh1, acc, 0, 0, 0);
                f32x4 mw = mw4[mt2];
                float u0 = exp2f(fminf(acc[0], 60.f));
                float u1 = exp2f(fminf(acc[1], 60.f));
                float u2 = exp2f(fminf(acc[2], 60.f));
                float u3 = exp2f(fminf(acc[3], 60.f));
                float n01 = fmaf(mw[0], u1, fmaf(mw[1], u0, mw[0] + mw[1]));
                float d01 = fmaf(u0, u1, 1.0f + (u0 + u1));
                float n23 = fmaf(mw[2], u3, fmaf(mw[3], u2, mw[2] + mw[3]));
                float d23 = fmaf(u2, u3, 1.0f + (u2 + u3));
                lp = fmaf(n01, __builtin_amdgcn_rcpf(d01), lp);
                lp = fmaf(n23, __builtin_amdgcn_rcpf(d23), lp);
            }
            lp += __shfl_xor(lp, 16);
            lp += __shfl_xor(lp, 32);
            if (eh == 0) lp_own[jt] = lp;
            else if (lane < 16) lpP[iw * PJ + jt * 16 + rr] = lp;
        }
        __syncthreads();             // SYNC1: partials visible; X(c) reads done

        // early-issue next-chunk f32 reads (latency hides under combine)
        float4 v0, v1, v2, v3;
        if (c < 3) {
            const float* src = xf + ((c + 1) * 128 + rj) * ND + q0 * 4;
            v0 = *(const float4*)(src);
            v1 = *(const float4*)(src + 4);
            v2 = *(const float4*)(src + 8);
            v3 = *(const float4*)(src + 12);
        }

        if (eh == 0 && lane < 16) {
            #pragma unroll
            for (int jt = jt0; jt < 8; ++jt) {
                float t = lp_own[jt] + lpP[iw * PJ + jt * 16 + rr];
                probs[iw * PJ + jt * 16 + rr] = exp2f(fmaf(t, K2, nLam2));
            }
        }

        if (c < 3) {                 // convert + write X(c+1); safe post-SYNC1
            cvt_store(v0, Xh, Xl, rj * 64 + (((q0 + 0) * 4) ^ sw));
            cvt_store(v1, Xh, Xl, rj * 64 + (((q0 + 1) * 4) ^ sw));
            cvt_store(v2, Xh, Xl, rj * 64 + (((q0 + 2) * 4) ^ sw));
            cvt_store(v3, Xh, Xl, rj * 64 + (((q0 + 3) * 4) ^ sw));
        }
        __syncthreads();             // SYNC2: probs + X(c+1) visible

        // own rows only: j >= i0, coalesced
        {
            const int iw2 = tid >> 7, jl = tid & 127, j = jb + jl;
            if (j >= i0) {
                float p = fminf(probs[iw2 * PJ + jl], 1.0f);
                pb[(i0 + iw2) * NN + j] =
                    (unsigned short)__float2uint_rn(p * 65535.f);
            }
        }
    }
}

// Phase 2 + fused top-k: per (b, 16 rows): rebuild full prob row, exact
// integer row-sum, agg from LDS-staged Xc chunks, h/BN/SELU/score. The LAST
// block per batch (device-scope atomic count) then runs the exact top-k
// select + gather for its batch (deterministic: value-identical work).
__global__ __launch_bounds__(1024, 2)
void sast_agg_kernel(const float* __restrict__ x,
                     const unsigned short* __restrict__ p_buf,
                     const float* __restrict__ pwa_w,
                     const float* __restrict__ pwa_b,
                     const float* __restrict__ pwo_w,
                     const float* __restrict__ pwo_b,
                     const float* __restrict__ gma,
                     const float* __restrict__ bta,
                     const float* __restrict__ rmean,
                     const float* __restrict__ rvar,
                     const float* __restrict__ pool_w,
                     const float* __restrict__ pool_b,
                     float* __restrict__ ws_h,
                     float* __restrict__ ws_score,
                     int* __restrict__ cnt,
                     float* __restrict__ out)
{
    __shared__ alignas(16) float Xc[8192];                // 32 KB: 128 j x 64 e
    __shared__ alignas(16) unsigned short prow[16 * NN];  // 16 KB
    __shared__ alignas(16) unsigned short pcolT[NN * 16]; // 16 KB (j, col)
    __shared__ float xrow[16 * ND];                       // 4 KB
    __shared__ float aggsh[16 * ND];                      // 4 KB
    __shared__ int lastflag;

    const int tid  = threadIdx.x;
    const int w    = tid >> 6;          // wave = local row (0..15)
    const int lane = tid & 63;
    const int b    = blockIdx.x >> 5;
    const int i0   = (blockIdx.x & 31) * 16;
    const int i    = i0 + w;
    const float* xb = x + b * NN * ND;
    const unsigned short* pbb = p_buf + b * NN * NN;

    // stage own prob row (1/wave) + chunk 0 of x + transpose stripe + x rows
    gl2lds16(pbb + i * NN + (lane << 3), &prow[w << 9]);
    gl2lds16f(xb + w * 512 +       (lane << 2), &Xc[w * 512]);
    gl2lds16f(xb + w * 512 + 256 + (lane << 2), &Xc[w * 512 + 256]);
    for (int t = tid; t < i0 + 12; t += 1024) {   // p[t][i0..i0+15], 32B aligned
        *(uint4*)(&pcolT[t * 16])     = *(const uint4*)(pbb + t * NN + i0);
        *(uint4*)(&pcolT[t * 16 + 8]) = *(const uint4*)(pbb + t * NN + i0 + 8);
    }
    xrow[tid] = xb[i0 * ND + tid];                // 16 rows x 64, contiguous
    __syncthreads();                              // drains gl2lds + LDS writes

    // overlay transpose prefix (j < i0 + (w & ~3)) into own row; same-wave
    const int B = i0 + (w & ~3);
    for (int j = lane; j < B; j += 64)
        prow[(w << 9) + j] = pcolT[j * 16 + w];

    // exact integer row sum (512*65535 < 2^25)
    uint4 q = *(const uint4*)(&prow[(w << 9) + (lane << 3)]);
    unsigned us = (q.x & 0xffffu) + (q.x >> 16) + (q.y & 0xffffu) + (q.y >> 16)
                + (q.z & 0xffffu) + (q.z >> 16) + (q.w & 0xffffu) + (q.w >> 16);
    #pragma unroll
    for (int m = 32; m; m >>= 1) us += (unsigned)__shfl_xor((int)us, m);
    const float Sinv = __fdividef(1.0f, (float)us);

    float acc0 = 0.f, acc1 = 0.f;       // two chains; agg for e = lane
    for (int c = 0; c < 4; ++c) {
        if (c) {
            __syncthreads();            // prior chunk reads done
            gl2lds16f(xb + c * 8192 + w * 512 +       (lane << 2), &Xc[w * 512]);
            gl2lds16f(xb + c * 8192 + w * 512 + 256 + (lane << 2), &Xc[w * 512 + 256]);
            __syncthreads();            // drained
        }
        const int jb = c << 7;
        #pragma unroll 4
        for (int jl = 0; jl < 128; jl += 2) {
            unsigned pu = *(const unsigned*)(&prow[(w << 9) + jb + jl]);
            acc0 = fmaf((float)(pu & 0xffffu), Xc[jl * 64 + lane], acc0);
            acc1 = fmaf((float)(pu >> 16),     Xc[(jl + 1) * 64 + lane], acc1);
        }
    }
    aggsh[w * ND + lane] = (acc0 + acc1) * Sinv;   // same-wave write->read

    float hv = pwa_b[lane] + pwo_b[lane];
    #pragma unroll 4
    for (int d = 0; d < ND; ++d)
        hv = fmaf(aggsh[w * ND + d], pwa_w[d * ND + lane],
             fmaf(xrow[w * ND + d], pwo_w[d * ND + lane], hv));
    hv = (hv - rmean[lane]) * rsqrtf(rvar[lane] + 1e-5f) * gma[lane] + bta[lane];
    hv = hv > 0.f ? SELU_SCALE * hv
                  : SELU_SCALE * SELU_ALPHA * (__expf(hv) - 1.0f);
    ws_h[(b * NN + i) * ND + lane] = hv;
    float sc = hv * pool_w[lane];
    #pragma unroll
    for (int m = 32; m; m >>= 1) sc += __shfl_xor(sc, m);
    if (lane == 0)
        ws_score[b * NN + i] = __fdividef(1.0f, 1.0f + __expf(-(sc + pool_b[0])));

    // ---- last block of this batch runs top-k (select + gather) ----
    __threadfence();                    // release our ws_h/ws_score writes
    if (tid == 0)
        lastflag = (atomicAdd(&cnt[b], 1) == 31);
    __syncthreads();
    if (!lastflag) return;
    __threadfence();                    // acquire other blocks' writes

    float* s  = (float*)prow;           // 2 KB reuse
    int* sel  = (int*)pcolT;            // 1 KB reuse
    if (tid < NN) s[tid] = ws_score[b * NN + tid];
    __syncthreads();
    if (tid < NN) {
        const float v = s[tid];
        int rank = 0;
        for (int j = 0; j < NN; ++j) {
            float sj = s[j];
            rank += ((sj > v) || (sj == v && j < tid)) ? 1 : 0;
        }
        if (rank < NKEEP) sel[rank] = tid;
    }
    __syncthreads();
    #pragma unroll
    for (int it = 0; it < NKEEP * ND / 1024; ++it) {
        int f = it * 1024 + tid;
        int k = f >> 6, e = f & 63;
        int j = sel[k];
        out[(b * NKEEP + k) * ND + e] = ws_h[(b * NN + j) * ND + e] * s[j];
    }
}

extern "C" void kernel_launch(void* const* d_in, const int* in_sizes, int n_in,
                              void* d_out, int out_size, void* d_ws, size_t ws_size,
                              hipStream_t stream)
{
    const float* x      = (const float*)d_in[0];
    const float* att_w  = (const float*)d_in[1];
    const float* att_b  = (const float*)d_in[2];
    const float* att_wt = (const float*)d_in[3];
    const float* pwa_w  = (const float*)d_in[4];
    const float* pwa_b  = (const float*)d_in[5];
    const float* pwo_w  = (const float*)d_in[6];
    const float* pwo_b  = (const float*)d_in[7];
    const float* gma    = (const float*)d_in[8];
    const float* bta    = (const float*)d_in[9];
    const float* rmean  = (const float*)d_in[10];
    const float* rvar   = (const float*)d_in[11];
    const float* pool_w = (const float*)d_in[12];
    const float* pool_b = (const float*)d_in[13];
    float* out   = (float*)d_out;
    float* ws_h  = (float*)d_ws;                          // 1 MB
    float* ws_sc = ws_h + NB * NN * ND;                   // 16 KB
    unsigned short* p_buf = (unsigned short*)(ws_sc + NB * NN);    // 4 MB u16
    int* cnt = (int*)(p_buf + NB * NN * NN);                       // 32 B

    hipMemsetAsync(cnt, 0, NB * sizeof(int), stream);
    sast_logit_kernel<<<NB * 128, 512, 0, stream>>>(
        x, att_w, att_b, att_wt, p_buf);
    sast_agg_kernel<<<NB * 32, 1024, 0, stream>>>(
        x, p_buf, pwa_w, pwa_b, pwo_w, pwo_b,
        gma, bta, rmean, rvar, pool_w, pool_b, ws_h, ws_sc, cnt, out);
}

// Round 20
// 89.413 us; speedup vs baseline: 1.8265x; 1.8265x over previous
//
#include <hip/hip_runtime.h>

#define NB 8
#define NN 512
#define ND 64
#define NKEEP 256
#define PJ 132
#define WSCALE 2.8853900817779268f   // 2*log2(e): MFMA acc = 2*zeta*log2(e)
#define K2 0.72134752f               // log2(e)/2

#define SELU_SCALE 1.0507009873554805f
#define SELU_ALPHA 1.6732632423543773f

typedef __attribute__((ext_vector_type(8))) short short8;
typedef __attribute__((ext_vector_type(4))) float f32x4;

__device__ __forceinline__ unsigned short f2bf_rne(float f) {
    unsigned u = __float_as_uint(f);
    return (unsigned short)((u + 0x7fffu + ((u >> 16) & 1u)) >> 16);
}
__device__ __forceinline__ float bf2f(unsigned short h) {
    return __uint_as_float(((unsigned)h) << 16);
}

// async global->LDS, 16 bytes per lane; lds dest = wave-uniform base (+lane*16 in HW)
__device__ __forceinline__ void gl2lds16(const unsigned short* g, unsigned short* l) {
    __builtin_amdgcn_global_load_lds(
        (const __attribute__((address_space(1))) unsigned int*)g,
        (__attribute__((address_space(3))) unsigned int*)l,
        16, 0, 0);
}
__device__ __forceinline__ void gl2lds16f(const float* g, float* l) {
    __builtin_amdgcn_global_load_lds(
        (const __attribute__((address_space(1))) unsigned int*)g,
        (__attribute__((address_space(3))) unsigned int*)l,
        16, 0, 0);
}

__device__ __forceinline__ unsigned pack2(float a, float b) {
    return (unsigned)f2bf_rne(a) | ((unsigned)f2bf_rne(b) << 16);
}
__device__ __forceinline__ unsigned pack2lo(float a, unsigned short ha,
                                            float b, unsigned short hb) {
    unsigned la = __float_as_uint(a - bf2f(ha)) >> 16;
    unsigned lb = __float_as_uint(b - bf2f(hb)) & 0xffff0000u;
    return la | lb;
}

// convert TWO float4s (8 contiguous x values) into one b128 write each to
// Xh/Xl at 16B-aligned swizzled idx (pair offsets are contiguous: swizzle
// only touches bits >=3 of the u16 index). Bank-uniform across the wave.
__device__ __forceinline__ void cvt_store_pair(float4 va, float4 vb,
                                               unsigned short* Xh,
                                               unsigned short* Xl, int idx) {
    unsigned short h0 = f2bf_rne(va.x), h1 = f2bf_rne(va.y),
                   h2 = f2bf_rne(va.z), h3 = f2bf_rne(va.w),
                   h4 = f2bf_rne(vb.x), h5 = f2bf_rne(vb.y),
                   h6 = f2bf_rne(vb.z), h7 = f2bf_rne(vb.w);
    uint4 hw, lw;
    hw.x = (unsigned)h0 | ((unsigned)h1 << 16);
    hw.y = (unsigned)h2 | ((unsigned)h3 << 16);
    hw.z = (unsigned)h4 | ((unsigned)h5 << 16);
    hw.w = (unsigned)h6 | ((unsigned)h7 << 16);
    lw.x = pack2lo(va.x, h0, va.y, h1);
    lw.y = pack2lo(va.z, h2, va.w, h3);
    lw.z = pack2lo(vb.x, h4, vb.y, h5);
    lw.w = pack2lo(vb.z, h6, vb.w, h7);
    *(uint4*)(&Xh[idx]) = hw;
    *(uint4*)(&Xl[idx]) = lw;
}

// Phase 1 (R18 structure, b128 conversion writes): upper-triangle logits,
// R13 round-balanced decode, inline x->bf16 hi/lo conversion, restage
// early-issued after SYNC1 and converted before SYNC2.
__global__ __launch_bounds__(512, 4)
void sast_logit_kernel(const float* __restrict__ x,
                       const float* __restrict__ att_w,
                       const float* __restrict__ att_b,
                       const float* __restrict__ att_wt,
                       unsigned short* __restrict__ p_buf)
{
    __shared__ alignas(16) unsigned short Xh[8192];   // 16 KB swizzled image
    __shared__ alignas(16) unsigned short Xl[8192];
    __shared__ float probs[4 * PJ];
    __shared__ float lpP[4 * PJ];
    __shared__ float xg[4 * ND];

    const int tid  = threadIdx.x;
    const int w    = tid >> 6;          // wave 0..7
    const int iw   = w & 3;             // local i
    const int eh   = w >> 2;            // e-half 0/1
    const int lane = tid & 63;
    const int g    = lane >> 4;
    const int rr   = lane & 15;
    // round-balanced decode (R13)
    const int rnd  = blockIdx.x >> 8;          // 0..3 == c0
    const int m0   = blockIdx.x & 31;
    const int m    = (rnd & 1) ? (31 - m0) : m0;
    const int b    = (blockIdx.x >> 5) & 7;
    const int i0   = 128 * rnd + 4 * m;
    const int c0   = rnd;

    const float* xf = x + b * NN * ND;
    unsigned short* pb = p_buf + b * NN * NN;

    // conversion job: row rj (0..127) of chunk, float4 pairs at q0, q0+2
    const int rj = tid >> 2;
    const int q0 = (tid & 3) * 4;
    const int sw = (rj & 7) << 3;
    const int cidx0 = rj * 64 + (((q0 + 0) * 4) ^ sw);   // 16B-aligned
    const int cidx1 = rj * 64 + (((q0 + 2) * 4) ^ sw);   // 16B-aligned

    // nLam2 = -log2e * 0.5 * sum_e |attw|
    float sab = 0.f;
    #pragma unroll
    for (int e4 = 0; e4 < ND; e4 += 4) {
        float4 awv = *(const float4*)(att_wt + e4);
        sab += fabsf(awv.x) + fabsf(awv.y) + fabsf(awv.z) + fabsf(awv.w);
    }
    const float nLam2 = -K2 * sab;

    const int swz = (rr & 7) << 3;
    const int fb0 = rr * 64 + ((g * 8) ^ swz);
    const int fb1 = rr * 64 + ((g * 8 + 32) ^ swz);

    // ---- stage x_i rows ----
    if (tid < 256) xg[tid] = x[(b * NN + i0 + (tid >> 6)) * ND + (tid & 63)];

    // ---- chunk-c0 conversion BEFORE W-build ----
    {
        const float* src = xf + (c0 * 128 + rj) * ND + q0 * 4;
        float4 v0 = *(const float4*)(src);
        float4 v1 = *(const float4*)(src + 4);
        float4 v2 = *(const float4*)(src + 8);
        float4 v3 = *(const float4*)(src + 12);
        cvt_store_pair(v0, v1, Xh, Xl, cidx0);
        cvt_store_pair(v2, v3, Xh, Xl, cidx1);
    }
    __syncthreads();                 // xg + chunk-c0 image visible

    // W_i fragments for THIS e-half, hi/lo bf16, x 2log2e
    short8 Wh[2][2], Wl[2][2];
    #pragma unroll
    for (int mt2 = 0; mt2 < 2; ++mt2) {
        const int mt = eh * 2 + mt2;
        #pragma unroll
        for (int ks = 0; ks < 2; ++ks) {
            #pragma unroll
            for (int t = 0; t < 8; ++t) {
                int d = ks * 32 + g * 8 + t;
                int e = mt * 16 + rr;
                float wv = att_w[d * ND + e] * xg[iw * ND + d] * WSCALE;
                unsigned short hh = f2bf_rne(wv);
                unsigned short ll = (unsigned short)(__float_as_uint(wv - bf2f(hh)) >> 16);
                Wh[mt2][ks][t] = (short)hh;
                Wl[mt2][ks][t] = (short)ll;
            }
        }
    }
    f32x4 attb4[2], mw4[2];
    float basep = 0.f;
    #pragma unroll
    for (int mt2 = 0; mt2 < 2; ++mt2) {
        const int mt = eh * 2 + mt2;
        #pragma unroll
        for (int r = 0; r < 4; ++r) {
            int e = mt * 16 + g * 4 + r;
            float aw = att_wt[e];
            attb4[mt2][r] = att_b[e] * WSCALE;
            mw4[mt2][r]   = -2.0f * aw;
            basep += aw;
        }
    }

    for (int c = c0; c < 4; ++c) {
        const int jb = c << 7;
        const int jt0 = (i0 > jb) ? ((i0 - jb) >> 4) : 0;  // skip tiles below boundary

        float lp_own[8];
        #pragma unroll
        for (int jt = jt0; jt < 8; ++jt) {
            short8 bh0 = *(const short8*)(Xh + fb0 + jt * 1024);
            short8 bh1 = *(const short8*)(Xh + fb1 + jt * 1024);
            short8 bl0 = *(const short8*)(Xl + fb0 + jt * 1024);
            short8 bl1 = *(const short8*)(Xl + fb1 + jt * 1024);
            float lp = basep;
            #pragma unroll
            for (int mt2 = 0; mt2 < 2; ++mt2) {
                f32x4 acc = attb4[mt2];
                acc = __builtin_amdgcn_mfma_f32_16x16x32_bf16(Wh[mt2][0], bh0, acc, 0, 0, 0);
                acc = __builtin_amdgcn_mfma_f32_16x16x32_bf16(Wh[mt2][1], bh1, acc, 0, 0, 0);
                acc = __builtin_amdgcn_mfma_f32_16x16x32_bf16(Wh[mt2][0], bl0, acc, 0, 0, 0);
                acc = __builtin_amdgcn_mfma_f32_16x16x32_bf16(Wh[mt2][1], bl1, acc, 0, 0, 0);
                acc = __builtin_amdgcn_mfma_f32_16x16x32_bf16(Wl[mt2][0], bh0, acc, 0, 0, 0);
                acc = __builtin_amdgcn_mfma_f32_16x16x32_bf16(Wl[mt2][1], bh1, acc, 0, 0, 0);
                f32x4 mw = mw4[mt2];
                float u0 = exp2f(fminf(acc[0], 60.f));
                float u1 = exp2f(fminf(acc[1], 60.f));
                float u2 = exp2f(fminf(acc[2], 60.f));
                float u3 = exp2f(fminf(acc[3], 60.f));
                float n01 = fmaf(mw[0], u1, fmaf(mw[1], u0, mw[0] + mw[1]));
                float d01 = fmaf(u0, u1, 1.0f + (u0 + u1));
                float n23 = fmaf(mw[2], u3, fmaf(mw[3], u2, mw[2] + mw[3]));
                float d23 = fmaf(u2, u3, 1.0f + (u2 + u3));
                lp = fmaf(n01, __builtin_amdgcn_rcpf(d01), lp);
                lp = fmaf(n23, __builtin_amdgcn_rcpf(d23), lp);
            }
            lp += __shfl_xor(lp, 16);
            lp += __shfl_xor(lp, 32);
            if (eh == 0) lp_own[jt] = lp;
            else if (lane < 16) lpP[iw * PJ + jt * 16 + rr] = lp;
        }
        __syncthreads();             // SYNC1: partials visible; X(c) reads done

        // early-issue next-chunk f32 reads (latency hides under combine)
        float4 v0, v1, v2, v3;
        if (c < 3) {
            const float* src = xf + ((c + 1) * 128 + rj) * ND + q0 * 4;
            v0 = *(const float4*)(src);
            v1 = *(const float4*)(src + 4);
            v2 = *(const float4*)(src + 8);
            v3 = *(const float4*)(src + 12);
        }

        if (eh == 0 && lane < 16) {
            #pragma unroll
            for (int jt = jt0; jt < 8; ++jt) {
                float t = lp_own[jt] + lpP[iw * PJ + jt * 16 + rr];
                probs[iw * PJ + jt * 16 + rr] = exp2f(fmaf(t, K2, nLam2));
            }
        }

        if (c < 3) {                 // convert + write X(c+1); safe post-SYNC1
            cvt_store_pair(v0, v1, Xh, Xl, cidx0);
            cvt_store_pair(v2, v3, Xh, Xl, cidx1);
        }
        __syncthreads();             // SYNC2: probs + X(c+1) visible

        // own rows only: j >= i0, coalesced
        {
            const int iw2 = tid >> 7, jl = tid & 127, j = jb + jl;
            if (j >= i0) {
                float p = fminf(probs[iw2 * PJ + jl], 1.0f);
                pb[(i0 + iw2) * NN + j] =
                    (unsigned short)__float2uint_rn(p * 65535.f);
            }
        }
    }
}

// Phase 2 (R18-exact): per (b, 16 rows), 1024 threads (1 row/wave): rebuild
// full prob row (own + transpose prefix), exact integer row-sum, agg from
// LDS-staged Xc chunks, 2 acc chains, h/BN/SELU/score.
__global__ __launch_bounds__(1024, 2)
void sast_agg_kernel(const float* __restrict__ x,
                     const unsigned short* __restrict__ p_buf,
                     const float* __restrict__ pwa_w,
                     const float* __restrict__ pwa_b,
                     const float* __restrict__ pwo_w,
                     const float* __restrict__ pwo_b,
                     const float* __restrict__ gma,
                     const float* __restrict__ bta,
                     const float* __restrict__ rmean,
                     const float* __restrict__ rvar,
                     const float* __restrict__ pool_w,
                     const float* __restrict__ pool_b,
                     float* __restrict__ ws_h,
                     float* __restrict__ ws_score)
{
    __shared__ alignas(16) float Xc[8192];                // 32 KB: 128 j x 64 e
    __shared__ alignas(16) unsigned short prow[16 * NN];  // 16 KB
    __shared__ alignas(16) unsigned short pcolT[NN * 16]; // 16 KB (j, col)
    __shared__ float xrow[16 * ND];                       // 4 KB
    __shared__ float aggsh[16 * ND];                      // 4 KB

    const int tid  = threadIdx.x;
    const int w    = tid >> 6;          // wave = local row (0..15)
    const int lane = tid & 63;
    const int b    = blockIdx.x >> 5;
    const int i0   = (blockIdx.x & 31) * 16;
    const int i    = i0 + w;
    const float* xb = x + b * NN * ND;
    const unsigned short* pbb = p_buf + b * NN * NN;

    // stage own prob row (1/wave) + chunk 0 of x + transpose stripe + x rows
    gl2lds16(pbb + i * NN + (lane << 3), &prow[w << 9]);
    gl2lds16f(xb + w * 512 +       (lane << 2), &Xc[w * 512]);
    gl2lds16f(xb + w * 512 + 256 + (lane << 2), &Xc[w * 512 + 256]);
    for (int t = tid; t < i0 + 12; t += 1024) {   // p[t][i0..i0+15], 32B aligned
        *(uint4*)(&pcolT[t * 16])     = *(const uint4*)(pbb + t * NN + i0);
        *(uint4*)(&pcolT[t * 16 + 8]) = *(const uint4*)(pbb + t * NN + i0 + 8);
    }
    xrow[tid] = xb[i0 * ND + tid];                // 16 rows x 64, contiguous
    __syncthreads();                              // drains gl2lds + LDS writes

    // overlay transpose prefix (j < i0 + (w & ~3)) into own row; same-wave
    const int B = i0 + (w & ~3);
    for (int j = lane; j < B; j += 64)
        prow[(w << 9) + j] = pcolT[j * 16 + w];

    // exact integer row sum (512*65535 < 2^25)
    uint4 q = *(const uint4*)(&prow[(w << 9) + (lane << 3)]);
    unsigned us = (q.x & 0xffffu) + (q.x >> 16) + (q.y & 0xffffu) + (q.y >> 16)
                + (q.z & 0xffffu) + (q.z >> 16) + (q.w & 0xffffu) + (q.w >> 16);
    #pragma unroll
    for (int m = 32; m; m >>= 1) us += (unsigned)__shfl_xor((int)us, m);
    const float Sinv = __fdividef(1.0f, (float)us);

    float acc0 = 0.f, acc1 = 0.f;       // two chains; agg for e = lane
    for (int c = 0; c < 4; ++c) {
        if (c) {
            __syncthreads();            // prior chunk reads done
            gl2lds16f(xb + c * 8192 + w * 512 +       (lane << 2), &Xc[w * 512]);
            gl2lds16f(xb + c * 8192 + w * 512 + 256 + (lane << 2), &Xc[w * 512 + 256]);
            __syncthreads();            // drained
        }
        const int jb = c << 7;
        #pragma unroll 4
        for (int jl = 0; jl < 128; jl += 2) {
            unsigned pu = *(const unsigned*)(&prow[(w << 9) + jb + jl]);
            acc0 = fmaf((float)(pu & 0xffffu), Xc[jl * 64 + lane], acc0);
            acc1 = fmaf((float)(pu >> 16),     Xc[(jl + 1) * 64 + lane], acc1);
        }
    }
    aggsh[w * ND + lane] = (acc0 + acc1) * Sinv;   // same-wave write->read

    float hv = pwa_b[lane] + pwo_b[lane];
    #pragma unroll 4
    for (int d = 0; d < ND; ++d)
        hv = fmaf(aggsh[w * ND + d], pwa_w[d * ND + lane],
             fmaf(xrow[w * ND + d], pwo_w[d * ND + lane], hv));
    hv = (hv - rmean[lane]) * rsqrtf(rvar[lane] + 1e-5f) * gma[lane] + bta[lane];
    hv = hv > 0.f ? SELU_SCALE * hv
                  : SELU_SCALE * SELU_ALPHA * (__expf(hv) - 1.0f);
    ws_h[(b * NN + i) * ND + lane] = hv;
    float sc = hv * pool_w[lane];
    #pragma unroll
    for (int m = 32; m; m >>= 1) sc += __shfl_xor(sc, m);
    if (lane == 0)
        ws_score[b * NN + i] = __fdividef(1.0f, 1.0f + __expf(-(sc + pool_b[0])));
}

// Top-k (fused select + gather): exact stable rank (matches lax.top_k:
// descending, ties by lower index), then gather h*score.
__global__ void sast_topk_kernel(const float* __restrict__ ws_h,
                                 const float* __restrict__ ws_score,
                                 float* __restrict__ out)
{
    __shared__ float s[NN];
    __shared__ int sel[NKEEP];
    const int b = blockIdx.x, tid = threadIdx.x;   // 512 threads
    s[tid] = ws_score[b * NN + tid];
    __syncthreads();
    const float v = s[tid];
    int rank = 0;
    for (int j = 0; j < NN; ++j) {
        float sj = s[j];
        rank += ((sj > v) || (sj == v && j < tid)) ? 1 : 0;
    }
    if (rank < NKEEP) sel[rank] = tid;
    __syncthreads();
    #pragma unroll
    for (int it = 0; it < NKEEP * ND / 512; ++it) {
        int f = it * 512 + tid;
        int k = f >> 6, e = f & 63;
        int j = sel[k];
        out[(b * NKEEP + k) * ND + e] = ws_h[(b * NN + j) * ND + e] * s[j];
    }
}

extern "C" void kernel_launch(void* const* d_in, const int* in_sizes, int n_in,
                              void* d_out, int out_size, void* d_ws, size_t ws_size,
                              hipStream_t stream)
{
    const float* x      = (const float*)d_in[0];
    const float* att_w  = (const float*)d_in[1];
    const float* att_b  = (const float*)d_in[2];
    const float* att_wt = (const float*)d_in[3];
    const float* pwa_w  = (const float*)d_in[4];
    const float* pwa_b  = (const float*)d_in[5];
    const float* pwo_w  = (const float*)d_in[6];
    const float* pwo_b  = (const float*)d_in[7];
    const float* gma    = (const float*)d_in[8];
    const float* bta    = (const float*)d_in[9];
    const float* rmean  = (const float*)d_in[10];
    const float* rvar   = (const float*)d_in[11];
    const float* pool_w = (const float*)d_in[12];
    const float* pool_b = (const float*)d_in[13];
    float* out   = (float*)d_out;
    float* ws_h  = (float*)d_ws;                          // 1 MB
    float* ws_sc = ws_h + NB * NN * ND;                   // 16 KB
    unsigned short* p_buf = (unsigned short*)(ws_sc + NB * NN);    // 4 MB u16

    sast_logit_kernel<<<NB * 128, 512, 0, stream>>>(
        x, att_w, att_b, att_wt, p_buf);
    sast_agg_kernel<<<NB * 32, 1024, 0, stream>>>(
        x, p_buf, pwa_w, pwa_b, pwo_w, pwo_b,
        gma, bta, rmean, rvar, pool_w, pool_b, ws_h, ws_sc);
    sast_topk_kernel<<<NB, 512, 0, stream>>>(ws_h, ws_sc, out);
}

// Round 21
// 77.347 us; speedup vs baseline: 2.1115x; 1.1560x over previous
//
#include <hip/hip_runtime.h>

#define NB 8
#define NN 512
#define ND 64
#define NKEEP 256
#define PJ 132
#define WSCALE 2.8853900817779268f   // 2*log2(e): MFMA acc = 2*zeta*log2(e)
#define K2 0.72134752f               // log2(e)/2

#define SELU_SCALE 1.0507009873554805f
#define SELU_ALPHA 1.6732632423543773f

typedef __attribute__((ext_vector_type(8))) short short8;
typedef __attribute__((ext_vector_type(4))) float f32x4;

__device__ __forceinline__ unsigned short f2bf_rne(float f) {
    unsigned u = __float_as_uint(f);
    return (unsigned short)((u + 0x7fffu + ((u >> 16) & 1u)) >> 16);
}
__device__ __forceinline__ float bf2f(unsigned short h) {
    return __uint_as_float(((unsigned)h) << 16);
}

// async global->LDS, 16 bytes per lane; lds dest = wave-uniform base (+lane*16 in HW)
__device__ __forceinline__ void gl2lds16(const unsigned short* g, unsigned short* l) {
    __builtin_amdgcn_global_load_lds(
        (const __attribute__((address_space(1))) unsigned int*)g,
        (__attribute__((address_space(3))) unsigned int*)l,
        16, 0, 0);
}
__device__ __forceinline__ void gl2lds16f(const float* g, float* l) {
    __builtin_amdgcn_global_load_lds(
        (const __attribute__((address_space(1))) unsigned int*)g,
        (__attribute__((address_space(3))) unsigned int*)l,
        16, 0, 0);
}

__device__ __forceinline__ unsigned pack2lo(float a, unsigned short ha,
                                            float b, unsigned short hb) {
    unsigned la = __float_as_uint(a - bf2f(ha)) >> 16;
    unsigned lb = __float_as_uint(b - bf2f(hb)) & 0xffff0000u;
    return la | lb;
}

// convert TWO float4s (8 contiguous x values) into one b128 write each to
// Xh/Xl at 16B-aligned swizzled idx (pair offsets are contiguous: swizzle
// only touches bits >=3 of the u16 index). Bank-uniform across the wave.
__device__ __forceinline__ void cvt_store_pair(float4 va, float4 vb,
                                               unsigned short* Xh,
                                               unsigned short* Xl, int idx) {
    unsigned short h0 = f2bf_rne(va.x), h1 = f2bf_rne(va.y),
                   h2 = f2bf_rne(va.z), h3 = f2bf_rne(va.w),
                   h4 = f2bf_rne(vb.x), h5 = f2bf_rne(vb.y),
                   h6 = f2bf_rne(vb.z), h7 = f2bf_rne(vb.w);
    uint4 hw, lw;
    hw.x = (unsigned)h0 | ((unsigned)h1 << 16);
    hw.y = (unsigned)h2 | ((unsigned)h3 << 16);
    hw.z = (unsigned)h4 | ((unsigned)h5 << 16);
    hw.w = (unsigned)h6 | ((unsigned)h7 << 16);
    lw.x = pack2lo(va.x, h0, va.y, h1);
    lw.y = pack2lo(va.z, h2, va.w, h3);
    lw.z = pack2lo(vb.x, h4, vb.y, h5);
    lw.w = pack2lo(vb.z, h6, vb.w, h7);
    *(uint4*)(&Xh[idx]) = hw;
    *(uint4*)(&Xl[idx]) = lw;
}

// Phase 1 (R20-exact): upper-triangle logits, R13 round-balanced decode,
// inline x->bf16 hi/lo conversion (b128 writes), restage early-issued after
// SYNC1 and converted before SYNC2.
__global__ __launch_bounds__(512, 4)
void sast_logit_kernel(const float* __restrict__ x,
                       const float* __restrict__ att_w,
                       const float* __restrict__ att_b,
                       const float* __restrict__ att_wt,
                       unsigned short* __restrict__ p_buf)
{
    __shared__ alignas(16) unsigned short Xh[8192];   // 16 KB swizzled image
    __shared__ alignas(16) unsigned short Xl[8192];
    __shared__ float probs[4 * PJ];
    __shared__ float lpP[4 * PJ];
    __shared__ float xg[4 * ND];

    const int tid  = threadIdx.x;
    const int w    = tid >> 6;          // wave 0..7
    const int iw   = w & 3;             // local i
    const int eh   = w >> 2;            // e-half 0/1
    const int lane = tid & 63;
    const int g    = lane >> 4;
    const int rr   = lane & 15;
    // round-balanced decode (R13)
    const int rnd  = blockIdx.x >> 8;          // 0..3 == c0
    const int m0   = blockIdx.x & 31;
    const int m    = (rnd & 1) ? (31 - m0) : m0;
    const int b    = (blockIdx.x >> 5) & 7;
    const int i0   = 128 * rnd + 4 * m;
    const int c0   = rnd;

    const float* xf = x + b * NN * ND;
    unsigned short* pb = p_buf + b * NN * NN;

    // conversion job: row rj (0..127) of chunk, float4 pairs at q0, q0+2
    const int rj = tid >> 2;
    const int q0 = (tid & 3) * 4;
    const int sw = (rj & 7) << 3;
    const int cidx0 = rj * 64 + (((q0 + 0) * 4) ^ sw);   // 16B-aligned
    const int cidx1 = rj * 64 + (((q0 + 2) * 4) ^ sw);   // 16B-aligned

    // nLam2 = -log2e * 0.5 * sum_e |attw|
    float sab = 0.f;
    #pragma unroll
    for (int e4 = 0; e4 < ND; e4 += 4) {
        float4 awv = *(const float4*)(att_wt + e4);
        sab += fabsf(awv.x) + fabsf(awv.y) + fabsf(awv.z) + fabsf(awv.w);
    }
    const float nLam2 = -K2 * sab;

    const int swz = (rr & 7) << 3;
    const int fb0 = rr * 64 + ((g * 8) ^ swz);
    const int fb1 = rr * 64 + ((g * 8 + 32) ^ swz);

    // ---- stage x_i rows ----
    if (tid < 256) xg[tid] = x[(b * NN + i0 + (tid >> 6)) * ND + (tid & 63)];

    // ---- chunk-c0 conversion BEFORE W-build ----
    {
        const float* src = xf + (c0 * 128 + rj) * ND + q0 * 4;
        float4 v0 = *(const float4*)(src);
        float4 v1 = *(const float4*)(src + 4);
        float4 v2 = *(const float4*)(src + 8);
        float4 v3 = *(const float4*)(src + 12);
        cvt_store_pair(v0, v1, Xh, Xl, cidx0);
        cvt_store_pair(v2, v3, Xh, Xl, cidx1);
    }
    __syncthreads();                 // xg + chunk-c0 image visible

    // W_i fragments for THIS e-half, hi/lo bf16, x 2log2e
    short8 Wh[2][2], Wl[2][2];
    #pragma unroll
    for (int mt2 = 0; mt2 < 2; ++mt2) {
        const int mt = eh * 2 + mt2;
        #pragma unroll
        for (int ks = 0; ks < 2; ++ks) {
            #pragma unroll
            for (int t = 0; t < 8; ++t) {
                int d = ks * 32 + g * 8 + t;
                int e = mt * 16 + rr;
                float wv = att_w[d * ND + e] * xg[iw * ND + d] * WSCALE;
                unsigned short hh = f2bf_rne(wv);
                unsigned short ll = (unsigned short)(__float_as_uint(wv - bf2f(hh)) >> 16);
                Wh[mt2][ks][t] = (short)hh;
                Wl[mt2][ks][t] = (short)ll;
            }
        }
    }
    f32x4 attb4[2], mw4[2];
    float basep = 0.f;
    #pragma unroll
    for (int mt2 = 0; mt2 < 2; ++mt2) {
        const int mt = eh * 2 + mt2;
        #pragma unroll
        for (int r = 0; r < 4; ++r) {
            int e = mt * 16 + g * 4 + r;
            float aw = att_wt[e];
            attb4[mt2][r] = att_b[e] * WSCALE;
            mw4[mt2][r]   = -2.0f * aw;
            basep += aw;
        }
    }

    for (int c = c0; c < 4; ++c) {
        const int jb = c << 7;
        const int jt0 = (i0 > jb) ? ((i0 - jb) >> 4) : 0;  // skip tiles below boundary

        float lp_own[8];
        #pragma unroll
        for (int jt = jt0; jt < 8; ++jt) {
            short8 bh0 = *(const short8*)(Xh + fb0 + jt * 1024);
            short8 bh1 = *(const short8*)(Xh + fb1 + jt * 1024);
            short8 bl0 = *(const short8*)(Xl + fb0 + jt * 1024);
            short8 bl1 = *(const short8*)(Xl + fb1 + jt * 1024);
            float lp = basep;
            #pragma unroll
            for (int mt2 = 0; mt2 < 2; ++mt2) {
                f32x4 acc = attb4[mt2];
                acc = __builtin_amdgcn_mfma_f32_16x16x32_bf16(Wh[mt2][0], bh0, acc, 0, 0, 0);
                acc = __builtin_amdgcn_mfma_f32_16x16x32_bf16(Wh[mt2][1], bh1, acc, 0, 0, 0);
                acc = __builtin_amdgcn_mfma_f32_16x16x32_bf16(Wh[mt2][0], bl0, acc, 0, 0, 0);
                acc = __builtin_amdgcn_mfma_f32_16x16x32_bf16(Wh[mt2][1], bl1, acc, 0, 0, 0);
                acc = __builtin_amdgcn_mfma_f32_16x16x32_bf16(Wl[mt2][0], bh0, acc, 0, 0, 0);
                acc = __builtin_amdgcn_mfma_f32_16x16x32_bf16(Wl[mt2][1], bh1, acc, 0, 0, 0);
                f32x4 mw = mw4[mt2];
                float u0 = exp2f(fminf(acc[0], 60.f));
                float u1 = exp2f(fminf(acc[1], 60.f));
                float u2 = exp2f(fminf(acc[2], 60.f));
                float u3 = exp2f(fminf(acc[3], 60.f));
                float n01 = fmaf(mw[0], u1, fmaf(mw[1], u0, mw[0] + mw[1]));
                float d01 = fmaf(u0, u1, 1.0f + (u0 + u1));
                float n23 = fmaf(mw[2], u3, fmaf(mw[3], u2, mw[2] + mw[3]));
                float d23 = fmaf(u2, u3, 1.0f + (u2 + u3));
                lp = fmaf(n01, __builtin_amdgcn_rcpf(d01), lp);
                lp = fmaf(n23, __builtin_amdgcn_rcpf(d23), lp);
            }
            lp += __shfl_xor(lp, 16);
            lp += __shfl_xor(lp, 32);
            if (eh == 0) lp_own[jt] = lp;
            else if (lane < 16) lpP[iw * PJ + jt * 16 + rr] = lp;
        }
        __syncthreads();             // SYNC1: partials visible; X(c) reads done

        // early-issue next-chunk f32 reads (latency hides under combine)
        float4 v0, v1, v2, v3;
        if (c < 3) {
            const float* src = xf + ((c + 1) * 128 + rj) * ND + q0 * 4;
            v0 = *(const float4*)(src);
            v1 = *(const float4*)(src + 4);
            v2 = *(const float4*)(src + 8);
            v3 = *(const float4*)(src + 12);
        }

        if (eh == 0 && lane < 16) {
            #pragma unroll
            for (int jt = jt0; jt < 8; ++jt) {
                float t = lp_own[jt] + lpP[iw * PJ + jt * 16 + rr];
                probs[iw * PJ + jt * 16 + rr] = exp2f(fmaf(t, K2, nLam2));
            }
        }

        if (c < 3) {                 // convert + write X(c+1); safe post-SYNC1
            cvt_store_pair(v0, v1, Xh, Xl, cidx0);
            cvt_store_pair(v2, v3, Xh, Xl, cidx1);
        }
        __syncthreads();             // SYNC2: probs + X(c+1) visible

        // own rows only: j >= i0, coalesced
        {
            const int iw2 = tid >> 7, jl = tid & 127, j = jb + jl;
            if (j >= i0) {
                float p = fminf(probs[iw2 * PJ + jl], 1.0f);
                pb[(i0 + iw2) * NN + j] =
                    (unsigned short)__float2uint_rn(p * 65535.f);
            }
        }
    }
}

// Phase 2 (R20-exact): per (b, 16 rows), 1024 threads (1 row/wave): rebuild
// full prob row (own + transpose prefix), exact integer row-sum, agg from
// LDS-staged Xc chunks, 2 acc chains, h/BN/SELU/score.
__global__ __launch_bounds__(1024, 2)
void sast_agg_kernel(const float* __restrict__ x,
                     const unsigned short* __restrict__ p_buf,
                     const float* __restrict__ pwa_w,
                     const float* __restrict__ pwa_b,
                     const float* __restrict__ pwo_w,
                     const float* __restrict__ pwo_b,
                     const float* __restrict__ gma,
                     const float* __restrict__ bta,
                     const float* __restrict__ rmean,
                     const float* __restrict__ rvar,
                     const float* __restrict__ pool_w,
                     const float* __restrict__ pool_b,
                     float* __restrict__ ws_h,
                     float* __restrict__ ws_score)
{
    __shared__ alignas(16) float Xc[8192];                // 32 KB: 128 j x 64 e
    __shared__ alignas(16) unsigned short prow[16 * NN];  // 16 KB
    __shared__ alignas(16) unsigned short pcolT[NN * 16]; // 16 KB (j, col)
    __shared__ float xrow[16 * ND];                       // 4 KB
    __shared__ float aggsh[16 * ND];                      // 4 KB

    const int tid  = threadIdx.x;
    const int w    = tid >> 6;          // wave = local row (0..15)
    const int lane = tid & 63;
    const int b    = blockIdx.x >> 5;
    const int i0   = (blockIdx.x & 31) * 16;
    const int i    = i0 + w;
    const float* xb = x + b * NN * ND;
    const unsigned short* pbb = p_buf + b * NN * NN;

    // stage own prob row (1/wave) + chunk 0 of x + transpose stripe + x rows
    gl2lds16(pbb + i * NN + (lane << 3), &prow[w << 9]);
    gl2lds16f(xb + w * 512 +       (lane << 2), &Xc[w * 512]);
    gl2lds16f(xb + w * 512 + 256 + (lane << 2), &Xc[w * 512 + 256]);
    for (int t = tid; t < i0 + 12; t += 1024) {   // p[t][i0..i0+15], 32B aligned
        *(uint4*)(&pcolT[t * 16])     = *(const uint4*)(pbb + t * NN + i0);
        *(uint4*)(&pcolT[t * 16 + 8]) = *(const uint4*)(pbb + t * NN + i0 + 8);
    }
    xrow[tid] = xb[i0 * ND + tid];                // 16 rows x 64, contiguous
    __syncthreads();                              // drains gl2lds + LDS writes

    // overlay transpose prefix (j < i0 + (w & ~3)) into own row; same-wave
    const int B = i0 + (w & ~3);
    for (int j = lane; j < B; j += 64)
        prow[(w << 9) + j] = pcolT[j * 16 + w];

    // exact integer row sum (512*65535 < 2^25)
    uint4 q = *(const uint4*)(&prow[(w << 9) + (lane << 3)]);
    unsigned us = (q.x & 0xffffu) + (q.x >> 16) + (q.y & 0xffffu) + (q.y >> 16)
                + (q.z & 0xffffu) + (q.z >> 16) + (q.w & 0xffffu) + (q.w >> 16);
    #pragma unroll
    for (int m = 32; m; m >>= 1) us += (unsigned)__shfl_xor((int)us, m);
    const float Sinv = __fdividef(1.0f, (float)us);

    float acc0 = 0.f, acc1 = 0.f;       // two chains; agg for e = lane
    for (int c = 0; c < 4; ++c) {
        if (c) {
            __syncthreads();            // prior chunk reads done
            gl2lds16f(xb + c * 8192 + w * 512 +       (lane << 2), &Xc[w * 512]);
            gl2lds16f(xb + c * 8192 + w * 512 + 256 + (lane << 2), &Xc[w * 512 + 256]);
            __syncthreads();            // drained
        }
        const int jb = c << 7;
        #pragma unroll 4
        for (int jl = 0; jl < 128; jl += 2) {
            unsigned pu = *(const unsigned*)(&prow[(w << 9) + jb + jl]);
            acc0 = fmaf((float)(pu & 0xffffu), Xc[jl * 64 + lane], acc0);
            acc1 = fmaf((float)(pu >> 16),     Xc[(jl + 1) * 64 + lane], acc1);
        }
    }
    aggsh[w * ND + lane] = (acc0 + acc1) * Sinv;   // same-wave write->read

    float hv = pwa_b[lane] + pwo_b[lane];
    #pragma unroll 4
    for (int d = 0; d < ND; ++d)
        hv = fmaf(aggsh[w * ND + d], pwa_w[d * ND + lane],
             fmaf(xrow[w * ND + d], pwo_w[d * ND + lane], hv));
    hv = (hv - rmean[lane]) * rsqrtf(rvar[lane] + 1e-5f) * gma[lane] + bta[lane];
    hv = hv > 0.f ? SELU_SCALE * hv
                  : SELU_SCALE * SELU_ALPHA * (__expf(hv) - 1.0f);
    ws_h[(b * NN + i) * ND + lane] = hv;
    float sc = hv * pool_w[lane];
    #pragma unroll
    for (int m = 32; m; m >>= 1) sc += __shfl_xor(sc, m);
    if (lane == 0)
        ws_score[b * NN + i] = __fdividef(1.0f, 1.0f + __expf(-(sc + pool_b[0])));
}

// Top-k, parallelized: 64 blocks (8 per batch), 8 threads per candidate.
// Rank = #{j: s_j > v or (s_j == v and j < i)} — identical comparator to
// lax.top_k stable order. Selected candidates' 8 threads write their 8
// e-values of out[b][rank] directly (contiguous 64-float row).
__global__ __launch_bounds__(512)
void sast_topk_kernel(const float* __restrict__ ws_h,
                      const float* __restrict__ ws_score,
                      float* __restrict__ out)
{
    __shared__ float s[NN];
    const int tid = threadIdx.x;
    const int b   = blockIdx.x >> 3;
    const int g   = blockIdx.x & 7;
    s[tid] = ws_score[b * NN + tid];
    __syncthreads();
    const int c    = tid >> 3;          // candidate within group (0..63)
    const int part = tid & 7;           // j-range part (consecutive lanes)
    const int i    = g * 64 + c;
    const float v  = s[i];
    int rank = 0;
    #pragma unroll 8
    for (int j = part * 64; j < part * 64 + 64; ++j) {
        float sj = s[j];
        rank += ((sj > v) || (sj == v && j < i)) ? 1 : 0;
    }
    rank += __shfl_xor(rank, 1);
    rank += __shfl_xor(rank, 2);
    rank += __shfl_xor(rank, 4);
    if (rank < NKEEP) {
        const float* src = ws_h + (b * NN + i) * ND + part * 8;
        float* dst = out + (b * NKEEP + rank) * ND + part * 8;
        float4 a0 = *(const float4*)(src);
        float4 a1 = *(const float4*)(src + 4);
        a0.x *= v; a0.y *= v; a0.z *= v; a0.w *= v;
        a1.x *= v; a1.y *= v; a1.z *= v; a1.w *= v;
        *(float4*)(dst)     = a0;
        *(float4*)(dst + 4) = a1;
    }
}

extern "C" void kernel_launch(void* const* d_in, const int* in_sizes, int n_in,
                              void* d_out, int out_size, void* d_ws, size_t ws_size,
                              hipStream_t stream)
{
    const float* x      = (const float*)d_in[0];
    const float* att_w  = (const float*)d_in[1];
    const float* att_b  = (const float*)d_in[2];
    const float* att_wt = (const float*)d_in[3];
    const float* pwa_w  = (const float*)d_in[4];
    const float* pwa_b  = (const float*)d_in[5];
    const float* pwo_w  = (const float*)d_in[6];
    const float* pwo_b  = (const float*)d_in[7];
    const float* gma    = (const float*)d_in[8];
    const float* bta    = (const float*)d_in[9];
    const float* rmean  = (const float*)d_in[10];
    const float* rvar   = (const float*)d_in[11];
    const float* pool_w = (const float*)d_in[12];
    const float* pool_b = (const float*)d_in[13];
    float* out   = (float*)d_out;
    float* ws_h  = (float*)d_ws;                          // 1 MB
    float* ws_sc = ws_h + NB * NN * ND;                   // 16 KB
    unsigned short* p_buf = (unsigned short*)(ws_sc + NB * NN);    // 4 MB u16

    sast_logit_kernel<<<NB * 128, 512, 0, stream>>>(
        x, att_w, att_b, att_wt, p_buf);
    sast_agg_kernel<<<NB * 32, 1024, 0, stream>>>(
        x, p_buf, pwa_w, pwa_b, pwo_w, pwo_b,
        gma, bta, rmean, rvar, pool_w, pool_b, ws_h, ws_sc);
    sast_topk_kernel<<<NB * 8, 512, 0, stream>>>(ws_h, ws_sc, out);
}